// Round 2
// baseline (1551.230 us; speedup 1.0000x reference)
//
#include <hip/hip_runtime.h>
#include <hip/hip_bf16.h>

#define BN 4
#define TT 2305
#define CC 384
#define HH 6
#define DH 64
#define GW 48
#define BT 32
#define NT 73    // ceil(2305/32)
#define G  8     // tokens per block in K1/K3
#define NTG 289  // ceil(2305/8)

// ---------------------------------------------------------------------------
// K1: fused depthwise conv3x3 + BN + cls-concat + Q/K/V projection.
// One block per 8 tokens, 384 threads (one per channel). Conv rows in LDS;
// projection reads them as wave-uniform broadcasts (conflict-free) while
// each thread streams its W row (float4) once for all 8 tokens.
// Output layout: (B, H, T, DH) fp32.
// ---------------------------------------------------------------------------
__global__ __launch_bounds__(384)
void qkv_conv_proj(const float* __restrict__ x,
                   const float* __restrict__ kq, const float* __restrict__ kk, const float* __restrict__ kv,
                   const float* __restrict__ gq, const float* __restrict__ bq, const float* __restrict__ mq, const float* __restrict__ vq,
                   const float* __restrict__ gk, const float* __restrict__ bk, const float* __restrict__ mk, const float* __restrict__ vk,
                   const float* __restrict__ gv, const float* __restrict__ bv, const float* __restrict__ mv, const float* __restrict__ vv,
                   const float* __restrict__ Wq, const float* __restrict__ Wk, const float* __restrict__ Wv,
                   float* __restrict__ qp, float* __restrict__ kp, float* __restrict__ vp)
{
    const int n = blockIdx.x;
    const int b = n / NTG;
    const int t0 = (n % NTG) * G;
    const int c = threadIdx.x;

    __shared__ __align__(16) float rq[G][CC];
    __shared__ __align__(16) float rk[G][CC];
    __shared__ __align__(16) float rv[G][CC];

    const size_t xbase = (size_t)b * TT * CC;

    // depthwise conv + BN per token
    const float sq = gq[c] * rsqrtf(vq[c] + 1e-5f), oq = bq[c] - mq[c] * sq;
    const float sk = gk[c] * rsqrtf(vk[c] + 1e-5f), ok = bk[c] - mk[c] * sk;
    const float sv = gv[c] * rsqrtf(vv[c] + 1e-5f), ov = bv[c] - mv[c] * sv;
    float wq9[9], wk9[9], wv9[9];
    #pragma unroll
    for (int u = 0; u < 9; u++) {
        wq9[u] = kq[c * 9 + u];
        wk9[u] = kk[c * 9 + u];
        wv9[u] = kv[c * 9 + u];
    }

    for (int g = 0; g < G; g++) {
        const int t = t0 + g;
        if (t >= TT) break;
        if (t == 0) {
            float xv = x[xbase + c];
            rq[g][c] = xv; rk[g][c] = xv; rv[g][c] = xv;
        } else {
            const int s = t - 1, i = s / GW, j = s % GW;
            float aq = 0.f, ak = 0.f, av = 0.f;
            #pragma unroll
            for (int di = 0; di < 3; di++) {
                int ii = i + di - 1;
                if (ii < 0 || ii >= GW) continue;
                #pragma unroll
                for (int dj = 0; dj < 3; dj++) {
                    int jj = j + dj - 1;
                    if (jj < 0 || jj >= GW) continue;
                    float xv = x[xbase + (size_t)(1 + ii * GW + jj) * CC + c];
                    int u = di * 3 + dj;
                    aq += xv * wq9[u];
                    ak += xv * wk9[u];
                    av += xv * wv9[u];
                }
            }
            rq[g][c] = aq * sq + oq;
            rk[g][c] = ak * sk + ok;
            rv[g][c] = av * sv + ov;
        }
    }
    __syncthreads();

    const float4* wqr = (const float4*)(Wq + (size_t)c * CC);
    const float4* wkr = (const float4*)(Wk + (size_t)c * CC);
    const float4* wvr = (const float4*)(Wv + (size_t)c * CC);
    float aq2[G], ak2[G], av2[G];
    #pragma unroll
    for (int g = 0; g < G; g++) { aq2[g] = 0.f; ak2[g] = 0.f; av2[g] = 0.f; }

    #pragma unroll 2
    for (int v8 = 0; v8 < CC / 8; v8++) {
        float4 wq0 = wqr[2 * v8], wq1 = wqr[2 * v8 + 1];
        float4 wk0 = wkr[2 * v8], wk1 = wkr[2 * v8 + 1];
        float4 wv0 = wvr[2 * v8], wv1 = wvr[2 * v8 + 1];
        #pragma unroll
        for (int g = 0; g < G; g++) {
            float4 q0 = *(const float4*)&rq[g][v8 * 8], q1 = *(const float4*)&rq[g][v8 * 8 + 4];
            float4 k0 = *(const float4*)&rk[g][v8 * 8], k1 = *(const float4*)&rk[g][v8 * 8 + 4];
            float4 v0 = *(const float4*)&rv[g][v8 * 8], v1 = *(const float4*)&rv[g][v8 * 8 + 4];
            aq2[g] += q0.x * wq0.x + q0.y * wq0.y + q0.z * wq0.z + q0.w * wq0.w
                    + q1.x * wq1.x + q1.y * wq1.y + q1.z * wq1.z + q1.w * wq1.w;
            ak2[g] += k0.x * wk0.x + k0.y * wk0.y + k0.z * wk0.z + k0.w * wk0.w
                    + k1.x * wk1.x + k1.y * wk1.y + k1.z * wk1.z + k1.w * wk1.w;
            av2[g] += v0.x * wv0.x + v0.y * wv0.y + v0.z * wv0.z + v0.w * wv0.w
                    + v1.x * wv1.x + v1.y * wv1.y + v1.z * wv1.z + v1.w * wv1.w;
        }
    }
    const int hd = c / DH, d = c % DH;
    #pragma unroll
    for (int g = 0; g < G; g++) {
        const int t = t0 + g;
        if (t >= TT) break;
        const size_t oi = ((((size_t)b * HH + hd) * TT) + t) * DH + d;
        qp[oi] = aq2[g]; kp[oi] = ak2[g]; vp[oi] = av2[g];
    }
}

// ---------------------------------------------------------------------------
// K2: flash-style attention with online softmax. One block per (b, head,
// 32-row q tile); 256 threads.
// ---------------------------------------------------------------------------
__global__ __launch_bounds__(256)
void flash_attn(const float* __restrict__ qp, const float* __restrict__ kp,
                const float* __restrict__ vp, float* __restrict__ att)
{
    const int bid = blockIdx.x;
    const int lt = bid % NT;
    const int bh = bid / NT;
    const int hd = bh % HH, b = bh / HH;
    const int l0 = lt * BT;
    const size_t base = (((size_t)b * HH + hd) * TT) * (size_t)DH;
    const float* qb = qp + base;
    const float* kb = kp + base;
    const float* vb = vp + base;

    __shared__ float qs[BT][DH + 1];
    __shared__ __align__(16) float ksT[DH][36];
    __shared__ __align__(16) float vs[BT][DH];
    __shared__ float sc[BT][33];
    __shared__ float mrow[BT], lrow[BT], arow[BT];

    const int tid = threadIdx.x;
    for (int idx = tid; idx < BT * DH; idx += 256) {
        int r = idx >> 6, d = idx & 63;
        int l = l0 + r;
        qs[r][d] = (l < TT) ? qb[(size_t)l * DH + d] : 0.f;
    }
    if (tid < BT) { mrow[tid] = -1e30f; lrow[tid] = 0.f; }

    float acc[8];
    #pragma unroll
    for (int i = 0; i < 8; i++) acc[i] = 0.f;
    const int rs = tid >> 3;
    const int c0 = (tid & 7) * 4;
    const int d0 = (tid & 7) * 8;
    const float scale = 0.05103103630798288f;  // 384^-0.5

    for (int tc = 0; tc < NT; tc++) {
        const int t0 = tc * BT;
        __syncthreads();
        for (int idx = tid; idx < BT * DH; idx += 256) {
            int tr = idx >> 6, d = idx & 63;
            int t = t0 + tr;
            float kvl = (t < TT) ? kb[(size_t)t * DH + d] : 0.f;
            float vvl = (t < TT) ? vb[(size_t)t * DH + d] : 0.f;
            ksT[d][tr] = kvl;
            vs[tr][d] = vvl;
        }
        __syncthreads();

        float s0 = 0.f, s1 = 0.f, s2 = 0.f, s3 = 0.f;
        #pragma unroll 8
        for (int d = 0; d < DH; d++) {
            float qv = qs[rs][d];
            float4 k4 = *(const float4*)&ksT[d][c0];
            s0 += qv * k4.x; s1 += qv * k4.y; s2 += qv * k4.z; s3 += qv * k4.w;
        }
        const int tv = t0 + c0;
        sc[rs][c0 + 0] = (tv + 0 < TT) ? s0 * scale : -1e30f;
        sc[rs][c0 + 1] = (tv + 1 < TT) ? s1 * scale : -1e30f;
        sc[rs][c0 + 2] = (tv + 2 < TT) ? s2 * scale : -1e30f;
        sc[rs][c0 + 3] = (tv + 3 < TT) ? s3 * scale : -1e30f;
        __syncthreads();

        if (tid < BT) {
            const int r = tid;
            float mold = mrow[r];
            float cm = mold;
            #pragma unroll
            for (int j = 0; j < BT; j++) cm = fmaxf(cm, sc[r][j]);
            float al = __expf(mold - cm);
            float ps = 0.f;
            #pragma unroll
            for (int j = 0; j < BT; j++) {
                float p = __expf(sc[r][j] - cm);
                sc[r][j] = p;
                ps += p;
            }
            lrow[r] = lrow[r] * al + ps;
            mrow[r] = cm;
            arow[r] = al;
        }
        __syncthreads();

        const float al = arow[rs];
        #pragma unroll
        for (int i = 0; i < 8; i++) acc[i] *= al;
        #pragma unroll 4
        for (int j = 0; j < BT; j++) {
            float p = sc[rs][j];
            float4 v0 = *(const float4*)&vs[j][d0];
            float4 v1 = *(const float4*)&vs[j][d0 + 4];
            acc[0] += p * v0.x; acc[1] += p * v0.y; acc[2] += p * v0.z; acc[3] += p * v0.w;
            acc[4] += p * v1.x; acc[5] += p * v1.y; acc[6] += p * v1.z; acc[7] += p * v1.w;
        }
    }

    const float inv = 1.0f / lrow[rs];
    const int l = l0 + rs;
    if (l < TT) {
        float4 o0 = make_float4(acc[0] * inv, acc[1] * inv, acc[2] * inv, acc[3] * inv);
        float4 o1 = make_float4(acc[4] * inv, acc[5] * inv, acc[6] * inv, acc[7] * inv);
        float* op = att + ((size_t)b * TT + l) * CC + hd * DH + d0;
        *(float4*)op = o0;
        *(float4*)(op + 4) = o1;
    }
}

// ---------------------------------------------------------------------------
// K3: output projection + bias. One block per 8 tokens, 384 threads.
// ---------------------------------------------------------------------------
__global__ __launch_bounds__(384)
void out_proj(const float* __restrict__ att, const float* __restrict__ Wo,
              const float* __restrict__ bo, float* __restrict__ out)
{
    const int n = blockIdx.x;
    const int b = n / NTG;
    const int t0 = (n % NTG) * G;
    const int c = threadIdx.x;

    __shared__ __align__(16) float row[G][CC];
    for (int g = 0; g < G; g++) {
        const int t = t0 + g;
        if (t >= TT) break;
        row[g][c] = att[((size_t)b * TT + t) * CC + c];
    }
    __syncthreads();

    const float4* wor = (const float4*)(Wo + (size_t)c * CC);
    const float bias = bo[c];
    float acc[G];
    #pragma unroll
    for (int g = 0; g < G; g++) acc[g] = 0.f;

    #pragma unroll 2
    for (int v8 = 0; v8 < CC / 8; v8++) {
        float4 w0 = wor[2 * v8], w1 = wor[2 * v8 + 1];
        #pragma unroll
        for (int g = 0; g < G; g++) {
            float4 r0 = *(const float4*)&row[g][v8 * 8], r1 = *(const float4*)&row[g][v8 * 8 + 4];
            acc[g] += r0.x * w0.x + r0.y * w0.y + r0.z * w0.z + r0.w * w0.w
                    + r1.x * w1.x + r1.y * w1.y + r1.z * w1.z + r1.w * w1.w;
        }
    }
    #pragma unroll
    for (int g = 0; g < G; g++) {
        const int t = t0 + g;
        if (t >= TT) break;
        out[((size_t)b * TT + t) * CC + c] = acc[g] + bias;
    }
}

// ---------------------------------------------------------------------------
extern "C" void kernel_launch(void* const* d_in, const int* in_sizes, int n_in,
                              void* d_out, int out_size, void* d_ws, size_t ws_size,
                              hipStream_t stream)
{
    const float* x  = (const float*)d_in[0];
    // d_in[1] = h (48), d_in[2] = w (48): compile-time constants here.
    const float* kq = (const float*)d_in[3];
    const float* kk = (const float*)d_in[4];
    const float* kv = (const float*)d_in[5];
    const float* gq = (const float*)d_in[6];
    const float* bq = (const float*)d_in[7];
    const float* mq = (const float*)d_in[8];
    const float* vq = (const float*)d_in[9];
    const float* gk = (const float*)d_in[10];
    const float* bk = (const float*)d_in[11];
    const float* mk = (const float*)d_in[12];
    const float* vk = (const float*)d_in[13];
    const float* gv = (const float*)d_in[14];
    const float* bv = (const float*)d_in[15];
    const float* mv = (const float*)d_in[16];
    const float* vv = (const float*)d_in[17];
    const float* Wq = (const float*)d_in[18];
    const float* Wk = (const float*)d_in[19];
    const float* Wv = (const float*)d_in[20];
    const float* Wo = (const float*)d_in[21];
    const float* bo = (const float*)d_in[22];

    float* ws = (float*)d_ws;
    const size_t NE = (size_t)BN * TT * CC;   // 3,540,480
    float* qp  = ws;
    float* kp  = ws + NE;
    float* vp  = ws + 2 * NE;
    float* att = ws + 3 * NE;

    qkv_conv_proj<<<BN * NTG, CC, 0, stream>>>(x, kq, kk, kv,
                                               gq, bq, mq, vq,
                                               gk, bk, mk, vk,
                                               gv, bv, mv, vv,
                                               Wq, Wk, Wv, qp, kp, vp);
    flash_attn<<<BN * HH * NT, 256, 0, stream>>>(qp, kp, vp, att);
    out_proj<<<BN * NTG, CC, 0, stream>>>(att, Wo, bo, (float*)d_out);
}

// Round 3
// 379.175 us; speedup vs baseline: 4.0911x; 4.0911x over previous
//
#include <hip/hip_runtime.h>
#include <hip/hip_bf16.h>

#define BN 4
#define TT 2305
#define CC 384
#define HH 6
#define DH 64
#define GW 48
#define BH (BN*HH)          // 24
#define TP 2368             // 37*64, padded T
#define MT 37               // k/m tiles of 64 in flash
#define MF 9220             // BN*TT flattened tokens
#define MP 9280             // 145*64 padded
#define MB 145              // m-blocks in GEMMs
#define SCALE 0.05103103630798288f

typedef __hip_bfloat16 bf16;
typedef __attribute__((ext_vector_type(8))) short short8;
typedef __attribute__((ext_vector_type(4))) float floatx4;

#define MFMA(a,b,c) __builtin_amdgcn_mfma_f32_16x16x32_bf16((a),(b),(c),0,0,0)

// ---------------------------------------------------------------------------
// K1: depthwise conv3x3 + BN (+ cls passthrough), bf16 output rows (M,C).
// One block per 8 tokens, 384 threads (one per channel).
// ---------------------------------------------------------------------------
__global__ __launch_bounds__(384)
void conv_bn(const float* __restrict__ x,
             const float* __restrict__ kq, const float* __restrict__ kk, const float* __restrict__ kv,
             const float* __restrict__ gq, const float* __restrict__ bq, const float* __restrict__ mq, const float* __restrict__ vq,
             const float* __restrict__ gk, const float* __restrict__ bk, const float* __restrict__ mk, const float* __restrict__ vk,
             const float* __restrict__ gv, const float* __restrict__ bv, const float* __restrict__ mv, const float* __restrict__ vv,
             bf16* __restrict__ cq, bf16* __restrict__ ck, bf16* __restrict__ cv)
{
    const int n = blockIdx.x;
    const int b = n / 289;
    const int t0 = (n % 289) * 8;
    const int c = threadIdx.x;
    const size_t xbase = (size_t)b * TT * CC;

    const float sq = gq[c] * rsqrtf(vq[c] + 1e-5f), oq = bq[c] - mq[c] * sq;
    const float sk = gk[c] * rsqrtf(vk[c] + 1e-5f), ok = bk[c] - mk[c] * sk;
    const float sv = gv[c] * rsqrtf(vv[c] + 1e-5f), ov = bv[c] - mv[c] * sv;
    float wq9[9], wk9[9], wv9[9];
    #pragma unroll
    for (int u = 0; u < 9; u++) {
        wq9[u] = kq[c * 9 + u]; wk9[u] = kk[c * 9 + u]; wv9[u] = kv[c * 9 + u];
    }

    for (int g = 0; g < 8; g++) {
        const int t = t0 + g;
        if (t >= TT) break;
        const size_t mrow = (size_t)(b * TT + t) * CC + c;
        if (t == 0) {
            bf16 xv = __float2bfloat16(x[xbase + c]);
            cq[mrow] = xv; ck[mrow] = xv; cv[mrow] = xv;
        } else {
            const int s = t - 1, i = s / GW, j = s % GW;
            float aq = 0.f, ak = 0.f, av = 0.f;
            #pragma unroll
            for (int di = 0; di < 3; di++) {
                int ii = i + di - 1;
                if (ii < 0 || ii >= GW) continue;
                #pragma unroll
                for (int dj = 0; dj < 3; dj++) {
                    int jj = j + dj - 1;
                    if (jj < 0 || jj >= GW) continue;
                    float xv = x[xbase + (size_t)(1 + ii * GW + jj) * CC + c];
                    int u = di * 3 + dj;
                    aq += xv * wq9[u]; ak += xv * wk9[u]; av += xv * wv9[u];
                }
            }
            cq[mrow] = __float2bfloat16(aq * sq + oq);
            ck[mrow] = __float2bfloat16(ak * sk + ok);
            cv[mrow] = __float2bfloat16(av * sv + ov);
        }
    }
}

// ---------------------------------------------------------------------------
// K2: QKV projection GEMM, bf16 MFMA 16x16x32, no LDS.
// grid = (145 m-tiles, 18 n-tiles of 64). N: [0,384)=q, [384,768)=k, [768,1152)=v.
// q,k -> (B,H,TP,64) row-major; v -> (B,H,64,TP) transposed.
// ---------------------------------------------------------------------------
__global__ __launch_bounds__(256)
void qkv_gemm(const bf16* __restrict__ cq, const bf16* __restrict__ ck, const bf16* __restrict__ cv,
              const bf16* __restrict__ Wq, const bf16* __restrict__ Wk, const bf16* __restrict__ Wv,
              bf16* __restrict__ q, bf16* __restrict__ k, bf16* __restrict__ vT)
{
    const int m0 = blockIdx.x * 64;
    const int n0 = blockIdx.y * 64;
    const int w = threadIdx.x >> 6, lane = threadIdx.x & 63;
    const int lm = lane & 15, q4 = lane >> 4;
    const int which = n0 / CC;        // 0=q 1=k 2=v (64-tiles never straddle)
    const int obase = n0 % CC;
    const bf16* A = (which == 0) ? cq : (which == 1) ? ck : cv;
    const bf16* W = (which == 0) ? Wq : (which == 1) ? Wk : Wv;

    const size_t arow = (size_t)(m0 + w * 16 + lm) * CC;
    floatx4 acc[4];
    #pragma unroll
    for (int n = 0; n < 4; n++) acc[n] = (floatx4){0.f, 0.f, 0.f, 0.f};

    #pragma unroll 4
    for (int kc = 0; kc < CC / 32; kc++) {
        short8 a = *(const short8*)(A + arow + kc * 32 + q4 * 8);
        #pragma unroll
        for (int n = 0; n < 4; n++) {
            short8 bf = *(const short8*)(W + (size_t)(obase + n * 16 + lm) * CC + kc * 32 + q4 * 8);
            acc[n] = MFMA(a, bf, acc[n]);
        }
    }

    #pragma unroll
    for (int n = 0; n < 4; n++) {
        const int o = obase + n * 16 + lm;
        const int h = o >> 6, d = o & 63;
        #pragma unroll
        for (int r = 0; r < 4; r++) {
            const int m = m0 + w * 16 + q4 * 4 + r;
            if (m >= MF) continue;
            const int b = m / TT, t = m % TT;
            bf16 val = __float2bfloat16(acc[n][r]);
            if (which == 0)
                q[((size_t)(b * HH + h) * TP + t) * DH + d] = val;
            else if (which == 1)
                k[((size_t)(b * HH + h) * TP + t) * DH + d] = val;
            else
                vT[((size_t)(b * HH + h) * DH + d) * TP + t] = val;
        }
    }
}

// ---------------------------------------------------------------------------
// K3: flash attention, bf16 MFMA. grid = (37 m-tiles, 24 b*h).
// Block: 256 thr = 4 waves, each wave owns 16 q-rows. K/V^T staged in LDS
// (stride 72 bf16), P round-trips through LDS (m120 pattern).
// Output att: (MF, C) bf16 rows, head-major cols.
// ---------------------------------------------------------------------------
__global__ __launch_bounds__(256)
void flash(const bf16* __restrict__ q, const bf16* __restrict__ k,
           const bf16* __restrict__ vT, bf16* __restrict__ att)
{
    const int m0 = blockIdx.x * 64;
    const int bh = blockIdx.y;
    const int b = bh / HH, h = bh % HH;
    const int tid = threadIdx.x;
    const int w = tid >> 6, lane = tid & 63;
    const int lm = lane & 15, q4 = lane >> 4;
    const size_t qkbase = (size_t)bh * TP * DH;

    __shared__ __align__(16) bf16 Ks[64][72];
    __shared__ __align__(16) bf16 Vs[64][72];
    __shared__ __align__(16) bf16 Ps[4][16][72];

    short8 aq0, aq1;
    {
        const bf16* qrow = q + qkbase + (size_t)(m0 + w * 16 + lm) * DH;
        aq0 = *(const short8*)(qrow + q4 * 8);
        aq1 = *(const short8*)(qrow + 32 + q4 * 8);
    }

    floatx4 of[4];
    #pragma unroll
    for (int dt = 0; dt < 4; dt++) of[dt] = (floatx4){0.f, 0.f, 0.f, 0.f};
    float mrow[4], lrow[4];
    #pragma unroll
    for (int r = 0; r < 4; r++) { mrow[r] = -1e30f; lrow[r] = 0.f; }

    for (int t0 = 0; t0 < TP; t0 += 64) {
        __syncthreads();
        #pragma unroll
        for (int u = 0; u < 2; u++) {
            const int ch = tid + u * 256;           // 512 chunks of 16B
            const int tr = ch >> 3, c8 = ch & 7;
            *(uint4*)&Ks[tr][c8 * 8] =
                *(const uint4*)(k + qkbase + (size_t)(t0 + tr) * DH + c8 * 8);
            *(uint4*)&Vs[tr][c8 * 8] =
                *(const uint4*)(vT + qkbase + (size_t)tr * TP + t0 + c8 * 8);
        }
        __syncthreads();

        // S = Q K^T (16x64 strip per wave)
        floatx4 s[4];
        #pragma unroll
        for (int nt = 0; nt < 4; nt++) {
            s[nt] = (floatx4){0.f, 0.f, 0.f, 0.f};
            short8 b0 = *(const short8*)&Ks[nt * 16 + lm][q4 * 8];
            short8 b1 = *(const short8*)&Ks[nt * 16 + lm][32 + q4 * 8];
            s[nt] = MFMA(aq0, b0, s[nt]);
            s[nt] = MFMA(aq1, b1, s[nt]);
        }

        // mask + scale
        #pragma unroll
        for (int nt = 0; nt < 4; nt++) {
            const bool valid = (t0 + nt * 16 + lm) < TT;
            #pragma unroll
            for (int r = 0; r < 4; r++)
                s[nt][r] = valid ? s[nt][r] * SCALE : -1e30f;
        }

        // online softmax (rows live in 16-lane groups)
        float rmax[4], rsum[4], alpha[4];
        #pragma unroll
        for (int r = 0; r < 4; r++)
            rmax[r] = fmaxf(fmaxf(s[0][r], s[1][r]), fmaxf(s[2][r], s[3][r]));
        #pragma unroll
        for (int off = 1; off < 16; off <<= 1)
            #pragma unroll
            for (int r = 0; r < 4; r++)
                rmax[r] = fmaxf(rmax[r], __shfl_xor(rmax[r], off));
        #pragma unroll
        for (int r = 0; r < 4; r++) {
            float mn = fmaxf(mrow[r], rmax[r]);
            alpha[r] = __expf(mrow[r] - mn);
            mrow[r] = mn;
            rsum[r] = 0.f;
        }
        #pragma unroll
        for (int nt = 0; nt < 4; nt++)
            #pragma unroll
            for (int r = 0; r < 4; r++) {
                float p = __expf(s[nt][r] - mrow[r]);
                s[nt][r] = p;
                rsum[r] += p;
            }
        #pragma unroll
        for (int off = 1; off < 16; off <<= 1)
            #pragma unroll
            for (int r = 0; r < 4; r++)
                rsum[r] += __shfl_xor(rsum[r], off);
        #pragma unroll
        for (int r = 0; r < 4; r++)
            lrow[r] = lrow[r] * alpha[r] + rsum[r];
        #pragma unroll
        for (int dt = 0; dt < 4; dt++)
            #pragma unroll
            for (int r = 0; r < 4; r++)
                of[dt][r] *= alpha[r];

        // P -> LDS (wave-local)
        #pragma unroll
        for (int nt = 0; nt < 4; nt++)
            #pragma unroll
            for (int r = 0; r < 4; r++)
                Ps[w][q4 * 4 + r][nt * 16 + lm] = __float2bfloat16(s[nt][r]);

        // O += P V
        short8 pa0 = *(const short8*)&Ps[w][lm][q4 * 8];
        short8 pa1 = *(const short8*)&Ps[w][lm][32 + q4 * 8];
        #pragma unroll
        for (int dt = 0; dt < 4; dt++) {
            short8 b0 = *(const short8*)&Vs[dt * 16 + lm][q4 * 8];
            short8 b1 = *(const short8*)&Vs[dt * 16 + lm][32 + q4 * 8];
            of[dt] = MFMA(pa0, b0, of[dt]);
            of[dt] = MFMA(pa1, b1, of[dt]);
        }
    }

    float inv[4];
    #pragma unroll
    for (int r = 0; r < 4; r++) inv[r] = 1.f / lrow[r];
    #pragma unroll
    for (int dt = 0; dt < 4; dt++)
        #pragma unroll
        for (int r = 0; r < 4; r++) {
            const int t = m0 + w * 16 + q4 * 4 + r;
            if (t < TT)
                att[(size_t)(b * TT + t) * CC + h * DH + dt * 16 + lm] =
                    __float2bfloat16(of[dt][r] * inv[r]);
        }
}

// ---------------------------------------------------------------------------
// K4: output projection GEMM + bias, fp32 out. grid = (145, 6).
// ---------------------------------------------------------------------------
__global__ __launch_bounds__(256)
void out_gemm(const bf16* __restrict__ att, const bf16* __restrict__ Wo_bf,
              const float* __restrict__ bo, float* __restrict__ out)
{
    const int m0 = blockIdx.x * 64;
    const int n0 = blockIdx.y * 64;
    const int w = threadIdx.x >> 6, lane = threadIdx.x & 63;
    const int lm = lane & 15, q4 = lane >> 4;

    const size_t arow = (size_t)(m0 + w * 16 + lm) * CC;
    floatx4 acc[4];
    #pragma unroll
    for (int n = 0; n < 4; n++) acc[n] = (floatx4){0.f, 0.f, 0.f, 0.f};

    #pragma unroll 4
    for (int kc = 0; kc < CC / 32; kc++) {
        short8 a = *(const short8*)(att + arow + kc * 32 + q4 * 8);
        #pragma unroll
        for (int n = 0; n < 4; n++) {
            short8 bf = *(const short8*)(Wo_bf + (size_t)(n0 + n * 16 + lm) * CC + kc * 32 + q4 * 8);
            acc[n] = MFMA(a, bf, acc[n]);
        }
    }

    #pragma unroll
    for (int n = 0; n < 4; n++) {
        const int o = n0 + n * 16 + lm;
        const float bias = bo[o];
        #pragma unroll
        for (int r = 0; r < 4; r++) {
            const int m = m0 + w * 16 + q4 * 4 + r;
            if (m < MF) out[(size_t)m * CC + o] = acc[n][r] + bias;
        }
    }
}

// ---------------------------------------------------------------------------
// K5: convert fp32 weight matrices to bf16 once per launch (cheap).
// ---------------------------------------------------------------------------
__global__ __launch_bounds__(256)
void cvt_w(const float* __restrict__ Wq, const float* __restrict__ Wk,
           const float* __restrict__ Wv, const float* __restrict__ Wo,
           bf16* __restrict__ q, bf16* __restrict__ k,
           bf16* __restrict__ v, bf16* __restrict__ o)
{
    const int i = blockIdx.x * 256 + threadIdx.x;
    if (i < CC * CC) {
        q[i] = __float2bfloat16(Wq[i]);
        k[i] = __float2bfloat16(Wk[i]);
        v[i] = __float2bfloat16(Wv[i]);
        o[i] = __float2bfloat16(Wo[i]);
    }
}

// ---------------------------------------------------------------------------
extern "C" void kernel_launch(void* const* d_in, const int* in_sizes, int n_in,
                              void* d_out, int out_size, void* d_ws, size_t ws_size,
                              hipStream_t stream)
{
    const float* x  = (const float*)d_in[0];
    const float* kq = (const float*)d_in[3];
    const float* kk = (const float*)d_in[4];
    const float* kv = (const float*)d_in[5];
    const float* gq = (const float*)d_in[6];
    const float* bq = (const float*)d_in[7];
    const float* mq = (const float*)d_in[8];
    const float* vq = (const float*)d_in[9];
    const float* gk = (const float*)d_in[10];
    const float* bk = (const float*)d_in[11];
    const float* mk = (const float*)d_in[12];
    const float* vk = (const float*)d_in[13];
    const float* gv = (const float*)d_in[14];
    const float* bv = (const float*)d_in[15];
    const float* mv = (const float*)d_in[16];
    const float* vv = (const float*)d_in[17];
    const float* Wq = (const float*)d_in[18];
    const float* Wk = (const float*)d_in[19];
    const float* Wv = (const float*)d_in[20];
    const float* Wo = (const float*)d_in[21];
    const float* bo = (const float*)d_in[22];

    char* ws = (char*)d_ws;
    const size_t SZ_CONV = (size_t)MP * CC * 2;        // 7,127,040 B
    const size_t SZ_QK   = (size_t)BH * TP * DH * 2;   // 7,274,496 B
    const size_t SZ_W    = (size_t)CC * CC * 2;        //   294,912 B
    bf16* cq  = (bf16*)(ws);
    bf16* ck  = (bf16*)(ws + SZ_CONV);
    bf16* cv  = (bf16*)(ws + 2 * SZ_CONV);
    bf16* qb  = (bf16*)(ws + 3 * SZ_CONV);
    bf16* kb  = (bf16*)(ws + 3 * SZ_CONV + SZ_QK);
    bf16* vTb = (bf16*)(ws + 3 * SZ_CONV + 2 * SZ_QK);
    bf16* attb= (bf16*)(ws + 3 * SZ_CONV + 3 * SZ_QK);
    bf16* wqb = (bf16*)(ws + 3 * SZ_CONV + 3 * SZ_QK + SZ_CONV);
    bf16* wkb = (bf16*)(ws + 3 * SZ_CONV + 3 * SZ_QK + SZ_CONV + SZ_W);
    bf16* wvb = (bf16*)(ws + 3 * SZ_CONV + 3 * SZ_QK + SZ_CONV + 2 * SZ_W);
    bf16* wob = (bf16*)(ws + 3 * SZ_CONV + 3 * SZ_QK + SZ_CONV + 3 * SZ_W);

    cvt_w<<<(CC * CC + 255) / 256, 256, 0, stream>>>(Wq, Wk, Wv, Wo, wqb, wkb, wvb, wob);
    conv_bn<<<BN * 289, 384, 0, stream>>>(x, kq, kk, kv,
                                          gq, bq, mq, vq,
                                          gk, bk, mk, vk,
                                          gv, bv, mv, vv, cq, ck, cv);
    qkv_gemm<<<dim3(MB, 18), 256, 0, stream>>>(cq, ck, cv, wqb, wkb, wvb, qb, kb, vTb);
    flash<<<dim3(MT, BH), 256, 0, stream>>>(qb, kb, vTb, attb);
    out_gemm<<<dim3(MB, 6), 256, 0, stream>>>(attb, wob, bo, (float*)d_out);
}

// Round 5
// 340.793 us; speedup vs baseline: 4.5518x; 1.1126x over previous
//
#include <hip/hip_runtime.h>
#include <hip/hip_bf16.h>

#define BN 4
#define TT 2305
#define CC 384
#define HH 6
#define DH 64
#define GW 48
#define BH (BN*HH)          // 24
#define TP 2368             // 37*64, padded T for K/V
#define TQP 2560            // q buffer rows (10*256 coverage)
#define MF 9220             // BN*TT flattened tokens
#define MP 9280             // 145*64 padded
#define MB 145              // m-blocks in GEMMs
#define C2 0.07362223f      // 384^-0.5 * log2(e)

typedef __hip_bfloat16 bf16;
typedef __attribute__((ext_vector_type(8))) short short8;
typedef __attribute__((ext_vector_type(4))) float floatx4;
typedef __attribute__((ext_vector_type(16))) float floatx16;

#define MFMA16(a,b,c) __builtin_amdgcn_mfma_f32_16x16x32_bf16((a),(b),(c),0,0,0)
#define MFMA32(a,b,c) __builtin_amdgcn_mfma_f32_32x32x16_bf16((a),(b),(c),0,0,0)

__device__ __forceinline__ unsigned pack2(float a, float b) {
    bf16 lo = __float2bfloat16(a);
    bf16 hi = __float2bfloat16(b);
    unsigned short ul = *reinterpret_cast<unsigned short*>(&lo);
    unsigned short uh = *reinterpret_cast<unsigned short*>(&hi);
    return (unsigned)ul | ((unsigned)uh << 16);
}

// ---------------------------------------------------------------------------
// K1: depthwise conv3x3 + BN (+ cls passthrough), bf16 output rows (M,C).
// ---------------------------------------------------------------------------
__global__ __launch_bounds__(384)
void conv_bn(const float* __restrict__ x,
             const float* __restrict__ kq, const float* __restrict__ kk, const float* __restrict__ kv,
             const float* __restrict__ gq, const float* __restrict__ bq, const float* __restrict__ mq, const float* __restrict__ vq,
             const float* __restrict__ gk, const float* __restrict__ bk, const float* __restrict__ mk, const float* __restrict__ vk,
             const float* __restrict__ gv, const float* __restrict__ bv, const float* __restrict__ mv, const float* __restrict__ vv,
             bf16* __restrict__ cq, bf16* __restrict__ ck, bf16* __restrict__ cv)
{
    const int n = blockIdx.x;
    const int b = n / 289;
    const int t0 = (n % 289) * 8;
    const int c = threadIdx.x;
    const size_t xbase = (size_t)b * TT * CC;

    const float sq = gq[c] * rsqrtf(vq[c] + 1e-5f), oq = bq[c] - mq[c] * sq;
    const float sk = gk[c] * rsqrtf(vk[c] + 1e-5f), ok = bk[c] - mk[c] * sk;
    const float sv = gv[c] * rsqrtf(vv[c] + 1e-5f), ov = bv[c] - mv[c] * sv;
    float wq9[9], wk9[9], wv9[9];
    #pragma unroll
    for (int u = 0; u < 9; u++) {
        wq9[u] = kq[c * 9 + u]; wk9[u] = kk[c * 9 + u]; wv9[u] = kv[c * 9 + u];
    }

    for (int g = 0; g < 8; g++) {
        const int t = t0 + g;
        if (t >= TT) break;
        const size_t mrow = (size_t)(b * TT + t) * CC + c;
        if (t == 0) {
            bf16 xv = __float2bfloat16(x[xbase + c]);
            cq[mrow] = xv; ck[mrow] = xv; cv[mrow] = xv;
        } else {
            const int s = t - 1, i = s / GW, j = s % GW;
            float aq = 0.f, ak = 0.f, av = 0.f;
            #pragma unroll
            for (int di = 0; di < 3; di++) {
                int ii = i + di - 1;
                if (ii < 0 || ii >= GW) continue;
                #pragma unroll
                for (int dj = 0; dj < 3; dj++) {
                    int jj = j + dj - 1;
                    if (jj < 0 || jj >= GW) continue;
                    float xv = x[xbase + (size_t)(1 + ii * GW + jj) * CC + c];
                    int u = di * 3 + dj;
                    aq += xv * wq9[u]; ak += xv * wk9[u]; av += xv * wv9[u];
                }
            }
            cq[mrow] = __float2bfloat16(aq * sq + oq);
            ck[mrow] = __float2bfloat16(ak * sk + ok);
            cv[mrow] = __float2bfloat16(av * sv + ov);
        }
    }
}

// ---------------------------------------------------------------------------
// K2: QKV projection GEMM, bf16 MFMA 16x16x32.
// q -> (B,H,TQP,64); k -> (B,H,TP,64); v -> (B,H,64,TP) transposed.
// ---------------------------------------------------------------------------
__global__ __launch_bounds__(256)
void qkv_gemm(const bf16* __restrict__ cq, const bf16* __restrict__ ck, const bf16* __restrict__ cv,
              const bf16* __restrict__ Wq, const bf16* __restrict__ Wk, const bf16* __restrict__ Wv,
              bf16* __restrict__ q, bf16* __restrict__ k, bf16* __restrict__ vT)
{
    const int m0 = blockIdx.x * 64;
    const int n0 = blockIdx.y * 64;
    const int w = threadIdx.x >> 6, lane = threadIdx.x & 63;
    const int lm = lane & 15, q4 = lane >> 4;
    const int which = n0 / CC;
    const int obase = n0 % CC;
    const bf16* A = (which == 0) ? cq : (which == 1) ? ck : cv;
    const bf16* W = (which == 0) ? Wq : (which == 1) ? Wk : Wv;

    const size_t arow = (size_t)(m0 + w * 16 + lm) * CC;
    floatx4 acc[4];
    #pragma unroll
    for (int n = 0; n < 4; n++) acc[n] = (floatx4){0.f, 0.f, 0.f, 0.f};

    #pragma unroll 4
    for (int kc = 0; kc < CC / 32; kc++) {
        short8 a = *(const short8*)(A + arow + kc * 32 + q4 * 8);
        #pragma unroll
        for (int n = 0; n < 4; n++) {
            short8 bf = *(const short8*)(W + (size_t)(obase + n * 16 + lm) * CC + kc * 32 + q4 * 8);
            acc[n] = MFMA16(a, bf, acc[n]);
        }
    }

    #pragma unroll
    for (int n = 0; n < 4; n++) {
        const int o = obase + n * 16 + lm;
        const int h = o >> 6, d = o & 63;
        #pragma unroll
        for (int r = 0; r < 4; r++) {
            const int m = m0 + w * 16 + q4 * 4 + r;
            if (m >= MF) continue;
            const int b = m / TT, t = m % TT;
            bf16 val = __float2bfloat16(acc[n][r]);
            if (which == 0)
                q[((size_t)(b * HH + h) * TQP + t) * DH + d] = val;
            else if (which == 1)
                k[((size_t)(b * HH + h) * TP + t) * DH + d] = val;
            else
                vT[((size_t)(b * HH + h) * DH + d) * TP + t] = val;
        }
    }
}

// ---------------------------------------------------------------------------
// K3: flash attention, 32x32x16 MFMA, S^T trick, in-register P transpose.
// grid = (10 m-blocks of 256 q, 24 bh). 256 thr = 4 waves; wave owns 64 q
// (2 strips of 32). K/V^T staged in LDS with XOR-16B-chunk swizzle
// (conflict-free for both staging writes and A-frag reads).
// ---------------------------------------------------------------------------
__global__ __launch_bounds__(256, 1)
void flash(const bf16* __restrict__ q, const bf16* __restrict__ k,
           const bf16* __restrict__ vT, bf16* __restrict__ att)
{
    const int bh = blockIdx.y;
    const int b = bh / HH, h_head = bh % HH;
    const int tid = threadIdx.x;
    const int w = tid >> 6, lane = tid & 63;
    const int q31 = lane & 31, hh = lane >> 5;
    const int q0 = blockIdx.x * 256 + w * 64;
    const size_t kbase = (size_t)bh * TP * DH;
    const size_t qbase = (size_t)bh * TQP * DH;

    __shared__ __align__(16) bf16 Ks[64 * 64];
    __shared__ __align__(16) bf16 Vs[64 * 64];

    // Q B-frags: lane owns Q[q0+s*32+q31][kc*16 + hh*8 + j]
    short8 qf[2][4];
    #pragma unroll
    for (int s = 0; s < 2; s++) {
        const bf16* qrow = q + qbase + (size_t)(q0 + s * 32 + q31) * DH;
        #pragma unroll
        for (int kc = 0; kc < 4; kc++)
            qf[s][kc] = *(const short8*)(qrow + kc * 16 + hh * 8);
    }

    floatx16 of[2][2];
    #pragma unroll
    for (int s = 0; s < 2; s++)
        #pragma unroll
        for (int dt = 0; dt < 2; dt++)
            #pragma unroll
            for (int r = 0; r < 16; r++) of[s][dt][r] = 0.f;
    float m2[2] = {-1e30f, -1e30f}, lsum[2] = {0.f, 0.f};

    for (int t0 = 0; t0 < TP; t0 += 64) {
        __syncthreads();
        #pragma unroll
        for (int it = 0; it < 2; it++) {
            const int idx = tid + it * 256;
            const int tr = idx >> 3, c8 = idx & 7;
            *(uint4*)&Ks[tr * 64 + ((c8 ^ (tr & 7)) * 8)] =
                *(const uint4*)(k + kbase + (size_t)(t0 + tr) * DH + c8 * 8);
            *(uint4*)&Vs[tr * 64 + ((c8 ^ (tr & 7)) * 8)] =
                *(const uint4*)(vT + kbase + (size_t)tr * TP + t0 + c8 * 8);
        }
        __syncthreads();

        // K A-frags: lane owns K[t0 + mt*32+q31][kc*16 + hh*8 + j]
        short8 ka[2][4];
        #pragma unroll
        for (int mt = 0; mt < 2; mt++)
            #pragma unroll
            for (int kc = 0; kc < 4; kc++) {
                const int row = mt * 32 + q31, c = 2 * kc + hh;
                ka[mt][kc] = *(const short8*)&Ks[row * 64 + ((c ^ (row & 7)) * 8)];
            }
        const bool tail = (t0 + 64 > TT);

        #pragma unroll
        for (int s = 0; s < 2; s++) {
            // S^T = K · Q^T : lane owns S[q=q31][t0 + mt*32 + (reg&3)+8*(reg>>2)+4*hh]
            floatx16 sv[2];
            #pragma unroll
            for (int mt = 0; mt < 2; mt++)
                #pragma unroll
                for (int r = 0; r < 16; r++) sv[mt][r] = 0.f;
            #pragma unroll
            for (int kc = 0; kc < 4; kc++) {
                sv[0] = MFMA32(ka[0][kc], qf[s][kc], sv[0]);
                sv[1] = MFMA32(ka[1][kc], qf[s][kc], sv[1]);
            }
            if (tail) {
                #pragma unroll
                for (int mt = 0; mt < 2; mt++)
                    #pragma unroll
                    for (int r = 0; r < 16; r++) {
                        const int tl = t0 + mt * 32 + (r & 3) + 8 * (r >> 2) + 4 * hh;
                        if (tl >= TT) sv[mt][r] = -1e30f;
                    }
            }
            // online softmax (one q-row per lane; replicas in both halves)
            float rm = sv[0][0];
            #pragma unroll
            for (int r = 1; r < 16; r++) rm = fmaxf(rm, sv[0][r]);
            #pragma unroll
            for (int r = 0; r < 16; r++) rm = fmaxf(rm, sv[1][r]);
            rm = fmaxf(rm, __shfl_xor(rm, 32));
            const float mn = fmaxf(m2[s], rm * C2);
            const float alpha = __builtin_amdgcn_exp2f(m2[s] - mn);
            m2[s] = mn;
            const float negm = -mn;
            float rs = 0.f;
            unsigned pk[2][8];
            #pragma unroll
            for (int mt = 0; mt < 2; mt++)
                #pragma unroll
                for (int p = 0; p < 8; p++) {
                    const float p0 = __builtin_amdgcn_exp2f(fmaf(sv[mt][2 * p], C2, negm));
                    const float p1 = __builtin_amdgcn_exp2f(fmaf(sv[mt][2 * p + 1], C2, negm));
                    rs += p0 + p1;
                    pk[mt][p] = pack2(p0, p1);
                }
            rs += __shfl_xor(rs, 32);
            lsum[s] = lsum[s] * alpha + rs;
            #pragma unroll
            for (int dt = 0; dt < 2; dt++)
                #pragma unroll
                for (int r = 0; r < 16; r++) of[s][dt][r] *= alpha;

            // V^T A-frags: lane owns V^T[dt*32+q31][t-chunk 2kc+hh]
            short8 va[2][4];
            #pragma unroll
            for (int dt = 0; dt < 2; dt++)
                #pragma unroll
                for (int kc = 0; kc < 4; kc++) {
                    const int row = dt * 32 + q31, c = 2 * kc + hh;
                    va[dt][kc] = *(const short8*)&Vs[row * 64 + ((c ^ (row & 7)) * 8)];
                }

            // O^T += V^T · P^T ; P^T B-frag via half-wave exchange
            #pragma unroll
            for (int kc = 0; kc < 4; kc++) {
                const int u0 = 2 * kc, u1 = 2 * kc + 1;
                const unsigned P0a = pk[u0 >> 2][2 * (u0 & 3)];
                const unsigned P0b = pk[u0 >> 2][2 * (u0 & 3) + 1];
                const unsigned P1a = pk[u1 >> 2][2 * (u1 & 3)];
                const unsigned P1b = pk[u1 >> 2][2 * (u1 & 3) + 1];
                const unsigned X1 = hh ? P0a : P1a;
                const unsigned X2 = hh ? P0b : P1b;
                const unsigned Y1 = __shfl_xor(X1, 32);
                const unsigned Y2 = __shfl_xor(X2, 32);
                unsigned dw[4];
                dw[0] = hh ? Y1 : P0a;
                dw[1] = hh ? Y2 : P0b;
                dw[2] = hh ? P1a : Y1;
                dw[3] = hh ? P1b : Y2;
                short8 pb = *reinterpret_cast<short8*>(dw);
                of[s][0] = MFMA32(va[0][kc], pb, of[s][0]);
                of[s][1] = MFMA32(va[1][kc], pb, of[s][1]);
            }
        }
    }

    #pragma unroll
    for (int s = 0; s < 2; s++) {
        const int qrow = q0 + s * 32 + q31;
        if (qrow >= TT) continue;
        const float inv = 1.f / lsum[s];
        bf16* orow = att + (size_t)(b * TT + qrow) * CC + h_head * DH;
        #pragma unroll
        for (int dt = 0; dt < 2; dt++)
            #pragma unroll
            for (int p = 0; p < 4; p++) {
                const int d = dt * 32 + 8 * p + 4 * hh;
                unsigned lo = pack2(of[s][dt][4 * p] * inv, of[s][dt][4 * p + 1] * inv);
                unsigned hi = pack2(of[s][dt][4 * p + 2] * inv, of[s][dt][4 * p + 3] * inv);
                uint2 st = {lo, hi};
                *(uint2*)(orow + d) = st;
            }
    }
}

// ---------------------------------------------------------------------------
// K4: output projection GEMM + bias, fp32 out.
// ---------------------------------------------------------------------------
__global__ __launch_bounds__(256)
void out_gemm(const bf16* __restrict__ att, const bf16* __restrict__ Wo_bf,
              const float* __restrict__ bo, float* __restrict__ out)
{
    const int m0 = blockIdx.x * 64;
    const int n0 = blockIdx.y * 64;
    const int w = threadIdx.x >> 6, lane = threadIdx.x & 63;
    const int lm = lane & 15, q4 = lane >> 4;

    const size_t arow = (size_t)(m0 + w * 16 + lm) * CC;
    floatx4 acc[4];
    #pragma unroll
    for (int n = 0; n < 4; n++) acc[n] = (floatx4){0.f, 0.f, 0.f, 0.f};

    #pragma unroll 4
    for (int kc = 0; kc < CC / 32; kc++) {
        short8 a = *(const short8*)(att + arow + kc * 32 + q4 * 8);
        #pragma unroll
        for (int n = 0; n < 4; n++) {
            short8 bf = *(const short8*)(Wo_bf + (size_t)(n0 + n * 16 + lm) * CC + kc * 32 + q4 * 8);
            acc[n] = MFMA16(a, bf, acc[n]);
        }
    }

    #pragma unroll
    for (int n = 0; n < 4; n++) {
        const int o = n0 + n * 16 + lm;
        const float bias = bo[o];
        #pragma unroll
        for (int r = 0; r < 4; r++) {
            const int m = m0 + w * 16 + q4 * 4 + r;
            if (m < MF) out[(size_t)m * CC + o] = acc[n][r] + bias;
        }
    }
}

// ---------------------------------------------------------------------------
// K5: fp32 -> bf16 weight conversion.
// ---------------------------------------------------------------------------
__global__ __launch_bounds__(256)
void cvt_w(const float* __restrict__ Wq, const float* __restrict__ Wk,
           const float* __restrict__ Wv, const float* __restrict__ Wo,
           bf16* __restrict__ q, bf16* __restrict__ k,
           bf16* __restrict__ v, bf16* __restrict__ o)
{
    const int i = blockIdx.x * 256 + threadIdx.x;
    if (i < CC * CC) {
        q[i] = __float2bfloat16(Wq[i]);
        k[i] = __float2bfloat16(Wk[i]);
        v[i] = __float2bfloat16(Wv[i]);
        o[i] = __float2bfloat16(Wo[i]);
    }
}

// ---------------------------------------------------------------------------
extern "C" void kernel_launch(void* const* d_in, const int* in_sizes, int n_in,
                              void* d_out, int out_size, void* d_ws, size_t ws_size,
                              hipStream_t stream)
{
    const float* x  = (const float*)d_in[0];
    const float* kq = (const float*)d_in[3];
    const float* kk = (const float*)d_in[4];
    const float* kv = (const float*)d_in[5];
    const float* gq = (const float*)d_in[6];
    const float* bq = (const float*)d_in[7];
    const float* mq = (const float*)d_in[8];
    const float* vq = (const float*)d_in[9];
    const float* gk = (const float*)d_in[10];
    const float* bk = (const float*)d_in[11];
    const float* mk = (const float*)d_in[12];
    const float* vk = (const float*)d_in[13];
    const float* gv = (const float*)d_in[14];
    const float* bv = (const float*)d_in[15];
    const float* mv = (const float*)d_in[16];
    const float* vv = (const float*)d_in[17];
    const float* Wq = (const float*)d_in[18];
    const float* Wk = (const float*)d_in[19];
    const float* Wv = (const float*)d_in[20];
    const float* Wo = (const float*)d_in[21];
    const float* bo = (const float*)d_in[22];

    char* ws = (char*)d_ws;
    const size_t SZ_CONV = (size_t)MP * CC * 2;        // 7,127,040
    const size_t SZ_Q    = (size_t)BH * TQP * DH * 2;  // 7,864,320
    const size_t SZ_K    = (size_t)BH * TP * DH * 2;   // 7,274,496
    const size_t SZ_W    = (size_t)CC * CC * 2;        //   294,912
    size_t off = 0;
    bf16* cq   = (bf16*)(ws + off); off += SZ_CONV;
    bf16* ck   = (bf16*)(ws + off); off += SZ_CONV;
    bf16* cv   = (bf16*)(ws + off); off += SZ_CONV;
    bf16* qb   = (bf16*)(ws + off); off += SZ_Q;
    bf16* kb   = (bf16*)(ws + off); off += SZ_K;
    bf16* vTb  = (bf16*)(ws + off); off += SZ_K;
    bf16* attb = (bf16*)(ws + off); off += SZ_CONV;
    bf16* wqb  = (bf16*)(ws + off); off += SZ_W;
    bf16* wkb  = (bf16*)(ws + off); off += SZ_W;
    bf16* wvb  = (bf16*)(ws + off); off += SZ_W;
    bf16* wob  = (bf16*)(ws + off); off += SZ_W;

    cvt_w<<<(CC * CC + 255) / 256, 256, 0, stream>>>(Wq, Wk, Wv, Wo, wqb, wkb, wvb, wob);
    conv_bn<<<BN * 289, 384, 0, stream>>>(x, kq, kk, kv,
                                          gq, bq, mq, vq,
                                          gk, bk, mk, vk,
                                          gv, bv, mv, vv, cq, ck, cv);
    qkv_gemm<<<dim3(MB, 18), 256, 0, stream>>>(cq, ck, cv, wqb, wkb, wvb, qb, kb, vTb);
    flash<<<dim3(10, BH), 256, 0, stream>>>(qb, kb, vTb, attb);
    out_gemm<<<dim3(MB, 6), 256, 0, stream>>>(attb, wob, bo, (float*)d_out);
}

// Round 6
// 299.375 us; speedup vs baseline: 5.1816x; 1.1383x over previous
//
#include <hip/hip_runtime.h>
#include <hip/hip_bf16.h>

#define BN 4
#define TT 2305
#define CC 384
#define HH 6
#define DH 64
#define GW 48
#define BH (BN*HH)          // 24
#define TP 2368             // 37*64, padded T for K/V
#define TQP 2560            // q buffer rows (10*256 coverage)
#define MF 9220             // BN*TT flattened tokens
#define MP 9344             // 73*128 padded
#define MB2 73              // m-blocks of 128 in GEMMs
#define C2 0.07362223f      // 384^-0.5 * log2(e)

typedef __hip_bfloat16 bf16;
typedef __attribute__((ext_vector_type(8))) short short8;
typedef __attribute__((ext_vector_type(4))) float floatx4;
typedef __attribute__((ext_vector_type(16))) float floatx16;

#define MFMA16(a,b,c) __builtin_amdgcn_mfma_f32_16x16x32_bf16((a),(b),(c),0,0,0)
#define MFMA32(a,b,c) __builtin_amdgcn_mfma_f32_32x32x16_bf16((a),(b),(c),0,0,0)

__device__ __forceinline__ unsigned pack2(float a, float b) {
    bf16 lo = __float2bfloat16(a);
    bf16 hi = __float2bfloat16(b);
    unsigned short ul = *reinterpret_cast<unsigned short*>(&lo);
    unsigned short uh = *reinterpret_cast<unsigned short*>(&hi);
    return (unsigned)ul | ((unsigned)uh << 16);
}
__device__ __forceinline__ float bu2f(unsigned u16) {
    unsigned v = u16 << 16;
    return *reinterpret_cast<float*>(&v);
}

// ---------------------------------------------------------------------------
// K1: depthwise conv3x3 + BN (+ cls passthrough), bf16 output rows (M,C).
// ---------------------------------------------------------------------------
__global__ __launch_bounds__(384)
void conv_bn(const float* __restrict__ x,
             const float* __restrict__ kq, const float* __restrict__ kk, const float* __restrict__ kv,
             const float* __restrict__ gq, const float* __restrict__ bq, const float* __restrict__ mq, const float* __restrict__ vq,
             const float* __restrict__ gk, const float* __restrict__ bk, const float* __restrict__ mk, const float* __restrict__ vk,
             const float* __restrict__ gv, const float* __restrict__ bv, const float* __restrict__ mv, const float* __restrict__ vv,
             bf16* __restrict__ cq, bf16* __restrict__ ck, bf16* __restrict__ cv)
{
    const int n = blockIdx.x;
    const int b = n / 289;
    const int t0 = (n % 289) * 8;
    const int c = threadIdx.x;
    const size_t xbase = (size_t)b * TT * CC;

    const float sq = gq[c] * rsqrtf(vq[c] + 1e-5f), oq = bq[c] - mq[c] * sq;
    const float sk = gk[c] * rsqrtf(vk[c] + 1e-5f), ok = bk[c] - mk[c] * sk;
    const float sv = gv[c] * rsqrtf(vv[c] + 1e-5f), ov = bv[c] - mv[c] * sv;
    float wq9[9], wk9[9], wv9[9];
    #pragma unroll
    for (int u = 0; u < 9; u++) {
        wq9[u] = kq[c * 9 + u]; wk9[u] = kk[c * 9 + u]; wv9[u] = kv[c * 9 + u];
    }

    for (int g = 0; g < 8; g++) {
        const int t = t0 + g;
        if (t >= TT) break;
        const size_t mrow = (size_t)(b * TT + t) * CC + c;
        if (t == 0) {
            bf16 xv = __float2bfloat16(x[xbase + c]);
            cq[mrow] = xv; ck[mrow] = xv; cv[mrow] = xv;
        } else {
            const int s = t - 1, i = s / GW, j = s % GW;
            float aq = 0.f, ak = 0.f, av = 0.f;
            #pragma unroll
            for (int di = 0; di < 3; di++) {
                int ii = i + di - 1;
                if (ii < 0 || ii >= GW) continue;
                #pragma unroll
                for (int dj = 0; dj < 3; dj++) {
                    int jj = j + dj - 1;
                    if (jj < 0 || jj >= GW) continue;
                    float xv = x[xbase + (size_t)(1 + ii * GW + jj) * CC + c];
                    int u = di * 3 + dj;
                    aq += xv * wq9[u]; ak += xv * wk9[u]; av += xv * wv9[u];
                }
            }
            cq[mrow] = __float2bfloat16(aq * sq + oq);
            ck[mrow] = __float2bfloat16(ak * sk + ok);
            cv[mrow] = __float2bfloat16(av * sv + ov);
        }
    }
}

// ---------------------------------------------------------------------------
// K2: QKV projection GEMM, 128-row m-tiles (2 strips share B-frags).
// q -> (B,H,TQP,64); k -> (B,H,TP,64); v -> (B,H,64,TP) transposed.
// ---------------------------------------------------------------------------
__global__ __launch_bounds__(256)
void qkv_gemm(const bf16* __restrict__ cq, const bf16* __restrict__ ck, const bf16* __restrict__ cv,
              const bf16* __restrict__ Wq, const bf16* __restrict__ Wk, const bf16* __restrict__ Wv,
              bf16* __restrict__ q, bf16* __restrict__ k, bf16* __restrict__ vT)
{
    const int m0 = blockIdx.x * 128;
    const int n0 = blockIdx.y * 64;
    const int w = threadIdx.x >> 6, lane = threadIdx.x & 63;
    const int lm = lane & 15, q4 = lane >> 4;
    const int which = n0 / CC;
    const int obase = n0 % CC;
    const bf16* A = (which == 0) ? cq : (which == 1) ? ck : cv;
    const bf16* W = (which == 0) ? Wq : (which == 1) ? Wk : Wv;

    const size_t ar0 = (size_t)(m0 + w * 16 + lm) * CC;
    floatx4 acc[2][4];
    #pragma unroll
    for (int st = 0; st < 2; st++)
        #pragma unroll
        for (int n = 0; n < 4; n++) acc[st][n] = (floatx4){0.f, 0.f, 0.f, 0.f};

    #pragma unroll 4
    for (int kc = 0; kc < CC / 32; kc++) {
        short8 a0 = *(const short8*)(A + ar0 + kc * 32 + q4 * 8);
        short8 a1 = *(const short8*)(A + ar0 + (size_t)64 * CC + kc * 32 + q4 * 8);
        #pragma unroll
        for (int n = 0; n < 4; n++) {
            short8 bfr = *(const short8*)(W + (size_t)(obase + n * 16 + lm) * CC + kc * 32 + q4 * 8);
            acc[0][n] = MFMA16(a0, bfr, acc[0][n]);
            acc[1][n] = MFMA16(a1, bfr, acc[1][n]);
        }
    }

    #pragma unroll
    for (int st = 0; st < 2; st++)
        #pragma unroll
        for (int n = 0; n < 4; n++) {
            const int o = obase + n * 16 + lm;
            const int h = o >> 6, d = o & 63;
            #pragma unroll
            for (int r = 0; r < 4; r++) {
                const int m = m0 + st * 64 + w * 16 + q4 * 4 + r;
                if (m >= MF) continue;
                const int b = m / TT, t = m % TT;
                bf16 val = __float2bfloat16(acc[st][n][r]);
                if (which == 0)
                    q[((size_t)(b * HH + h) * TQP + t) * DH + d] = val;
                else if (which == 1)
                    k[((size_t)(b * HH + h) * TP + t) * DH + d] = val;
                else
                    vT[((size_t)(b * HH + h) * DH + d) * TP + t] = val;
            }
        }
}

// ---------------------------------------------------------------------------
// K3: flash attention, split-K x2 over key tiles, LDS double-buffered.
// grid = (10, 24 bh, 2 splits). Writes unnormalized O (bf16) + m,l (fp32).
// ---------------------------------------------------------------------------
__global__ __launch_bounds__(256, 2)
void flash(const bf16* __restrict__ q, const bf16* __restrict__ k,
           const bf16* __restrict__ vT, bf16* __restrict__ OP, float* __restrict__ ML)
{
    const int bh = blockIdx.y;
    const int z = blockIdx.z;
    const int tid = threadIdx.x;
    const int w = tid >> 6, lane = tid & 63;
    const int q31 = lane & 31, hh = lane >> 5;
    const int q0 = blockIdx.x * 256 + w * 64;
    const size_t kbase = (size_t)bh * TP * DH;
    const size_t qbase = (size_t)bh * TQP * DH;

    __shared__ __align__(16) bf16 Ks[2][64 * 64];
    __shared__ __align__(16) bf16 Vs[2][64 * 64];

    short8 qf[2][4];
    #pragma unroll
    for (int s = 0; s < 2; s++) {
        const bf16* qrow = q + qbase + (size_t)(q0 + s * 32 + q31) * DH;
        #pragma unroll
        for (int kc = 0; kc < 4; kc++)
            qf[s][kc] = *(const short8*)(qrow + kc * 16 + hh * 8);
    }

    floatx16 of[2][2];
    #pragma unroll
    for (int s = 0; s < 2; s++)
        #pragma unroll
        for (int dt = 0; dt < 2; dt++)
            #pragma unroll
            for (int r = 0; r < 16; r++) of[s][dt][r] = 0.f;
    float m2[2] = {-1e30f, -1e30f}, lsum[2] = {0.f, 0.f};

    const int tstart = z ? 19 : 0;
    const int tend   = z ? 37 : 19;

    const int sidx = tid, sidx2 = tid + 256;
    const int tr0 = sidx >> 3,  c80 = sidx & 7;
    const int tr1 = sidx2 >> 3, c81 = sidx2 & 7;
    const int so0 = tr0 * 64 + ((c80 ^ (tr0 & 7)) * 8);
    const int so1 = tr1 * 64 + ((c81 ^ (tr1 & 7)) * 8);

    uint4 kreg[2], vreg[2];
    {
        const int t0 = tstart * 64;
        kreg[0] = *(const uint4*)(k + kbase + (size_t)(t0 + tr0) * DH + c80 * 8);
        vreg[0] = *(const uint4*)(vT + kbase + (size_t)tr0 * TP + t0 + c80 * 8);
        kreg[1] = *(const uint4*)(k + kbase + (size_t)(t0 + tr1) * DH + c81 * 8);
        vreg[1] = *(const uint4*)(vT + kbase + (size_t)tr1 * TP + t0 + c81 * 8);
    }
    *(uint4*)&Ks[0][so0] = kreg[0];
    *(uint4*)&Vs[0][so0] = vreg[0];
    *(uint4*)&Ks[0][so1] = kreg[1];
    *(uint4*)&Vs[0][so1] = vreg[1];

    for (int tc = tstart; tc < tend; tc++) {
        const int cur = (tc - tstart) & 1;
        const int t0 = tc * 64;
        __syncthreads();
        const bool more = (tc + 1 < tend);
        if (more) {
            const int t1 = t0 + 64;
            kreg[0] = *(const uint4*)(k + kbase + (size_t)(t1 + tr0) * DH + c80 * 8);
            vreg[0] = *(const uint4*)(vT + kbase + (size_t)tr0 * TP + t1 + c80 * 8);
            kreg[1] = *(const uint4*)(k + kbase + (size_t)(t1 + tr1) * DH + c81 * 8);
            vreg[1] = *(const uint4*)(vT + kbase + (size_t)tr1 * TP + t1 + c81 * 8);
        }
        const bf16* Kc = Ks[cur];
        const bf16* Vc = Vs[cur];

        short8 ka[2][4], va[2][4];
        #pragma unroll
        for (int mt = 0; mt < 2; mt++)
            #pragma unroll
            for (int kc = 0; kc < 4; kc++) {
                const int row = mt * 32 + q31, c = 2 * kc + hh;
                ka[mt][kc] = *(const short8*)&Kc[row * 64 + ((c ^ (row & 7)) * 8)];
                va[mt][kc] = *(const short8*)&Vc[row * 64 + ((c ^ (row & 7)) * 8)];
            }
        const bool tail = (t0 + 64 > TT);

        #pragma unroll
        for (int s = 0; s < 2; s++) {
            floatx16 sv[2];
            #pragma unroll
            for (int mt = 0; mt < 2; mt++)
                #pragma unroll
                for (int r = 0; r < 16; r++) sv[mt][r] = 0.f;
            #pragma unroll
            for (int kc = 0; kc < 4; kc++) {
                sv[0] = MFMA32(ka[0][kc], qf[s][kc], sv[0]);
                sv[1] = MFMA32(ka[1][kc], qf[s][kc], sv[1]);
            }
            if (tail) {
                #pragma unroll
                for (int mt = 0; mt < 2; mt++)
                    #pragma unroll
                    for (int r = 0; r < 16; r++) {
                        const int tl = t0 + mt * 32 + (r & 3) + 8 * (r >> 2) + 4 * hh;
                        if (tl >= TT) sv[mt][r] = -1e30f;
                    }
            }
            float rm = sv[0][0];
            #pragma unroll
            for (int r = 1; r < 16; r++) rm = fmaxf(rm, sv[0][r]);
            #pragma unroll
            for (int r = 0; r < 16; r++) rm = fmaxf(rm, sv[1][r]);
            rm = fmaxf(rm, __shfl_xor(rm, 32));
            const float mn = fmaxf(m2[s], rm * C2);
            const float alpha = __builtin_amdgcn_exp2f(m2[s] - mn);
            m2[s] = mn;
            const float negm = -mn;
            float rs = 0.f;
            unsigned pk[2][8];
            #pragma unroll
            for (int mt = 0; mt < 2; mt++)
                #pragma unroll
                for (int p = 0; p < 8; p++) {
                    const float p0 = __builtin_amdgcn_exp2f(fmaf(sv[mt][2 * p], C2, negm));
                    const float p1 = __builtin_amdgcn_exp2f(fmaf(sv[mt][2 * p + 1], C2, negm));
                    rs += p0 + p1;
                    pk[mt][p] = pack2(p0, p1);
                }
            rs += __shfl_xor(rs, 32);
            lsum[s] = lsum[s] * alpha + rs;
            #pragma unroll
            for (int dt = 0; dt < 2; dt++)
                #pragma unroll
                for (int r = 0; r < 16; r++) of[s][dt][r] *= alpha;

            #pragma unroll
            for (int kc = 0; kc < 4; kc++) {
                const int u0 = 2 * kc, u1 = 2 * kc + 1;
                const unsigned P0a = pk[u0 >> 2][2 * (u0 & 3)];
                const unsigned P0b = pk[u0 >> 2][2 * (u0 & 3) + 1];
                const unsigned P1a = pk[u1 >> 2][2 * (u1 & 3)];
                const unsigned P1b = pk[u1 >> 2][2 * (u1 & 3) + 1];
                const unsigned X1 = hh ? P0a : P1a;
                const unsigned X2 = hh ? P0b : P1b;
                const unsigned Y1 = __shfl_xor(X1, 32);
                const unsigned Y2 = __shfl_xor(X2, 32);
                unsigned dw[4];
                dw[0] = hh ? Y1 : P0a;
                dw[1] = hh ? Y2 : P0b;
                dw[2] = hh ? P1a : Y1;
                dw[3] = hh ? P1b : Y2;
                short8 pb = *reinterpret_cast<short8*>(dw);
                of[s][0] = MFMA32(va[0][kc], pb, of[s][0]);
                of[s][1] = MFMA32(va[1][kc], pb, of[s][1]);
            }
        }

        if (more) {
            bf16* Kn = Ks[1 - cur];
            bf16* Vn = Vs[1 - cur];
            *(uint4*)&Kn[so0] = kreg[0];
            *(uint4*)&Vn[so0] = vreg[0];
            *(uint4*)&Kn[so1] = kreg[1];
            *(uint4*)&Vn[so1] = vreg[1];
        }
    }

    // store unnormalized partials
    #pragma unroll
    for (int s = 0; s < 2; s++) {
        const int qrow = q0 + s * 32 + q31;
        if (qrow >= TT) continue;
        bf16* orow = OP + ((size_t)(z * BH + bh) * 2560 + qrow) * DH;
        #pragma unroll
        for (int dt = 0; dt < 2; dt++)
            #pragma unroll
            for (int p = 0; p < 4; p++) {
                const int d = dt * 32 + 8 * p + 4 * hh;
                unsigned lo = pack2(of[s][dt][4 * p], of[s][dt][4 * p + 1]);
                unsigned hi = pack2(of[s][dt][4 * p + 2], of[s][dt][4 * p + 3]);
                uint2 st = {lo, hi};
                *(uint2*)(orow + d) = st;
            }
        if (hh == 0) {
            float2 ml = {m2[s], lsum[s]};
            *(float2*)&ML[((size_t)(z * BH + bh) * 2560 + qrow) * 2] = ml;
        }
    }
}

// ---------------------------------------------------------------------------
// K3b: merge the two split-K partials -> att (bf16, head-major cols).
// ---------------------------------------------------------------------------
__global__ __launch_bounds__(256)
void merge(const bf16* __restrict__ OP, const float* __restrict__ ML,
           bf16* __restrict__ att)
{
    const int idx = blockIdx.x * 256 + threadIdx.x;
    if (idx >= BH * TT * 16) return;
    const int quad = idx & 15;
    const int pair = idx >> 4;
    const int bh = pair / TT, row = pair % TT;
    const int b = bh / HH, h = bh % HH;
    const int d0 = quad * 4;

    const float2 ml0 = *(const float2*)&ML[((size_t)bh * 2560 + row) * 2];
    const float2 ml1 = *(const float2*)&ML[((size_t)(BH + bh) * 2560 + row) * 2];
    const float M = fmaxf(ml0.x, ml1.x);
    const float w0 = __builtin_amdgcn_exp2f(ml0.x - M);
    const float w1 = __builtin_amdgcn_exp2f(ml1.x - M);
    const float inv = 1.f / (ml0.y * w0 + ml1.y * w1);
    const float s0 = w0 * inv, s1 = w1 * inv;

    const uint2 a = *(const uint2*)&OP[((size_t)bh * 2560 + row) * DH + d0];
    const uint2 c = *(const uint2*)&OP[((size_t)(BH + bh) * 2560 + row) * DH + d0];
    float o0 = bu2f(a.x & 0xffffu) * s0 + bu2f(c.x & 0xffffu) * s1;
    float o1 = bu2f(a.x >> 16)     * s0 + bu2f(c.x >> 16)     * s1;
    float o2 = bu2f(a.y & 0xffffu) * s0 + bu2f(c.y & 0xffffu) * s1;
    float o3 = bu2f(a.y >> 16)     * s0 + bu2f(c.y >> 16)     * s1;

    uint2 st = {pack2(o0, o1), pack2(o2, o3)};
    *(uint2*)&att[((size_t)(b * TT + row) * CC) + h * DH + d0] = st;
}

// ---------------------------------------------------------------------------
// K4: output projection GEMM + bias, 128-row m-tiles, fp32 out.
// ---------------------------------------------------------------------------
__global__ __launch_bounds__(256)
void out_gemm(const bf16* __restrict__ att, const bf16* __restrict__ Wo_bf,
              const float* __restrict__ bo, float* __restrict__ out)
{
    const int m0 = blockIdx.x * 128;
    const int n0 = blockIdx.y * 64;
    const int w = threadIdx.x >> 6, lane = threadIdx.x & 63;
    const int lm = lane & 15, q4 = lane >> 4;

    const size_t ar0 = (size_t)(m0 + w * 16 + lm) * CC;
    floatx4 acc[2][4];
    #pragma unroll
    for (int st = 0; st < 2; st++)
        #pragma unroll
        for (int n = 0; n < 4; n++) acc[st][n] = (floatx4){0.f, 0.f, 0.f, 0.f};

    #pragma unroll 4
    for (int kc = 0; kc < CC / 32; kc++) {
        short8 a0 = *(const short8*)(att + ar0 + kc * 32 + q4 * 8);
        short8 a1 = *(const short8*)(att + ar0 + (size_t)64 * CC + kc * 32 + q4 * 8);
        #pragma unroll
        for (int n = 0; n < 4; n++) {
            short8 bfr = *(const short8*)(Wo_bf + (size_t)(n0 + n * 16 + lm) * CC + kc * 32 + q4 * 8);
            acc[0][n] = MFMA16(a0, bfr, acc[0][n]);
            acc[1][n] = MFMA16(a1, bfr, acc[1][n]);
        }
    }

    #pragma unroll
    for (int st = 0; st < 2; st++)
        #pragma unroll
        for (int n = 0; n < 4; n++) {
            const int o = n0 + n * 16 + lm;
            const float bias = bo[o];
            #pragma unroll
            for (int r = 0; r < 4; r++) {
                const int m = m0 + st * 64 + w * 16 + q4 * 4 + r;
                if (m < MF) out[(size_t)m * CC + o] = acc[st][n][r] + bias;
            }
        }
}

// ---------------------------------------------------------------------------
// K5: fp32 -> bf16 weight conversion.
// ---------------------------------------------------------------------------
__global__ __launch_bounds__(256)
void cvt_w(const float* __restrict__ Wq, const float* __restrict__ Wk,
           const float* __restrict__ Wv, const float* __restrict__ Wo,
           bf16* __restrict__ q, bf16* __restrict__ k,
           bf16* __restrict__ v, bf16* __restrict__ o)
{
    const int i = blockIdx.x * 256 + threadIdx.x;
    if (i < CC * CC) {
        q[i] = __float2bfloat16(Wq[i]);
        k[i] = __float2bfloat16(Wk[i]);
        v[i] = __float2bfloat16(Wv[i]);
        o[i] = __float2bfloat16(Wo[i]);
    }
}

// ---------------------------------------------------------------------------
extern "C" void kernel_launch(void* const* d_in, const int* in_sizes, int n_in,
                              void* d_out, int out_size, void* d_ws, size_t ws_size,
                              hipStream_t stream)
{
    const float* x  = (const float*)d_in[0];
    const float* kq = (const float*)d_in[3];
    const float* kk = (const float*)d_in[4];
    const float* kv = (const float*)d_in[5];
    const float* gq = (const float*)d_in[6];
    const float* bq = (const float*)d_in[7];
    const float* mq = (const float*)d_in[8];
    const float* vq = (const float*)d_in[9];
    const float* gk = (const float*)d_in[10];
    const float* bk = (const float*)d_in[11];
    const float* mk = (const float*)d_in[12];
    const float* vk = (const float*)d_in[13];
    const float* gv = (const float*)d_in[14];
    const float* bv = (const float*)d_in[15];
    const float* mv = (const float*)d_in[16];
    const float* vv = (const float*)d_in[17];
    const float* Wq = (const float*)d_in[18];
    const float* Wk = (const float*)d_in[19];
    const float* Wv = (const float*)d_in[20];
    const float* Wo = (const float*)d_in[21];
    const float* bo = (const float*)d_in[22];

    char* ws = (char*)d_ws;
    const size_t SZ_CONV = (size_t)MP * CC * 2;        // 7,176,192
    const size_t SZ_Q    = (size_t)BH * TQP * DH * 2;  // 7,864,320
    const size_t SZ_K    = (size_t)BH * TP * DH * 2;   // 7,274,496
    const size_t SZ_W    = (size_t)CC * CC * 2;        //   294,912
    size_t off = 0;
    bf16* cq   = (bf16*)(ws + off); off += SZ_CONV;
    bf16* ck   = (bf16*)(ws + off); off += SZ_CONV;
    bf16* cv   = (bf16*)(ws + off); off += SZ_CONV;
    bf16* qb   = (bf16*)(ws + off); off += SZ_Q;
    bf16* kb   = (bf16*)(ws + off); off += SZ_K;
    bf16* vTb  = (bf16*)(ws + off); off += SZ_K;
    bf16* attb = (bf16*)(ws + off); off += SZ_CONV;
    bf16* wqb  = (bf16*)(ws + off); off += SZ_W;
    bf16* wkb  = (bf16*)(ws + off); off += SZ_W;
    bf16* wvb  = (bf16*)(ws + off); off += SZ_W;
    bf16* wob  = (bf16*)(ws + off); off += SZ_W;

    // split-K partials alias the conv buffers (dead after qkv_gemm):
    // OP: 2*24*2560*64 bf16 = 15,728,640 B ; ML: 2*24*2560*2 fp32 = 983,040 B
    bf16*  OP = (bf16*)ws;
    float* ML = (float*)(ws + 2 * (size_t)BH * 2560 * DH * 2);

    cvt_w<<<(CC * CC + 255) / 256, 256, 0, stream>>>(Wq, Wk, Wv, Wo, wqb, wkb, wvb, wob);
    conv_bn<<<BN * 289, 384, 0, stream>>>(x, kq, kk, kv,
                                          gq, bq, mq, vq,
                                          gk, bk, mk, vk,
                                          gv, bv, mv, vv, cq, ck, cv);
    qkv_gemm<<<dim3(MB2, 18), 256, 0, stream>>>(cq, ck, cv, wqb, wkb, wvb, qb, kb, vTb);
    flash<<<dim3(10, BH, 2), 256, 0, stream>>>(qb, kb, vTb, OP, ML);
    merge<<<(BH * TT * 16 + 255) / 256, 256, 0, stream>>>(OP, ML, attb);
    out_gemm<<<dim3(MB2, 6), 256, 0, stream>>>(attb, wob, bo, (float*)d_out);
}